// Round 7
// baseline (464.619 us; speedup 1.0000x reference)
//
#include <hip/hip_runtime.h>

#define IN_CH 128
#define OUT_CH 64
#define TN 64            // nodes per gemm block
#define XS_STRIDE 132    // padded x-tile stride
#define WS_STRIDE 129    // padded W staging stride

#define NPB 64           // nodes per bucket (bucket = dst >> 6)
#define PBLOCKS 512      // partition grid size
#define CAP 16           // slots per (bucket, partition-block) cell — MUST stay pow2 (see j&(CAP-1))
#define MAXBUCKETS 1024  // LDS cursor capacity >= ceil(nNodes/NPB)

// fp32 -> bf16 (RNE)
__device__ __forceinline__ unsigned f2bf(float f) {
    unsigned u = __float_as_uint(f);
    return (u + 0x7FFFu + ((u >> 16) & 1u)) >> 16;
}

__device__ __forceinline__ void fma4(float4& acc, float s, const float4& wv) {
    acc.x += s * wv.x;
    acc.y += s * wv.y;
    acc.z += s * wv.z;
    acc.w += s * wv.w;
}

// ---------------- h = x @ W^T, h stored as bf16 pairs; also zero is handled by harness-independent writes ----------------
__global__ __launch_bounds__(256) void k_gemm(const float* __restrict__ x,
                                              const float* __restrict__ W,
                                              unsigned* __restrict__ h16,  // [node][32] bf16x2
                                              int nNodes) {
    __shared__ float smem[TN * XS_STRIDE + IN_CH * OUT_CH];
    float* u  = smem;                   // W staging (str 129) then x tile (str 132)
    float* wt = smem + TN * XS_STRIDE;  // wt[k][o]

    int tid = threadIdx.x;
    int nodeBase = blockIdx.x * TN;

    {
        const float4* W4 = (const float4*)W;
        for (int i = tid; i < IN_CH * OUT_CH / 4; i += 256) {
            float4 v = W4[i];
            int o = i >> 5;
            int k = (i & 31) * 4;
            float* d = u + o * WS_STRIDE + k;
            d[0] = v.x; d[1] = v.y; d[2] = v.z; d[3] = v.w;
        }
    }
    __syncthreads();
    {
        int o = tid & 63;
        int k0 = (tid >> 6) * 32;
#pragma unroll 8
        for (int k = k0; k < k0 + 32; ++k)
            wt[k * OUT_CH + o] = u[o * WS_STRIDE + k];
    }
    __syncthreads();
    {
        int remRows = nNodes - nodeBase;
        if (remRows > TN) remRows = TN;
        const float4* X4 = (const float4*)(x + (size_t)nodeBase * IN_CH);
        for (int i = tid; i < TN * IN_CH / 4; i += 256) {
            int r = i >> 5;
            int k = (i & 31) * 4;
            float4 v = make_float4(0.f, 0.f, 0.f, 0.f);
            if (r < remRows) v = X4[i];
            *(float4*)(u + r * XS_STRIDE + k) = v;
        }
    }
    __syncthreads();

    int tx = tid & 15;
    int ty = tid >> 4;

    float4 acc[4];
#pragma unroll
    for (int i = 0; i < 4; ++i) acc[i] = make_float4(0.f, 0.f, 0.f, 0.f);

    const float* wcol = wt + tx * 4;
#pragma unroll 4
    for (int k = 0; k < IN_CH; k += 4) {
        float4 w0 = *(const float4*)(wcol + (k + 0) * OUT_CH);
        float4 w1 = *(const float4*)(wcol + (k + 1) * OUT_CH);
        float4 w2 = *(const float4*)(wcol + (k + 2) * OUT_CH);
        float4 w3 = *(const float4*)(wcol + (k + 3) * OUT_CH);
#pragma unroll
        for (int i = 0; i < 4; ++i) {
            float4 a = *(const float4*)(u + (ty * 4 + i) * XS_STRIDE + k);
            fma4(acc[i], a.x, w0);
            fma4(acc[i], a.y, w1);
            fma4(acc[i], a.z, w2);
            fma4(acc[i], a.w, w3);
        }
    }

#pragma unroll
    for (int i = 0; i < 4; ++i) {
        int n = nodeBase + ty * 4 + i;
        if (n < nNodes) {
            uint2 pk;
            pk.x = f2bf(acc[i].x) | (f2bf(acc[i].y) << 16);
            pk.y = f2bf(acc[i].z) | (f2bf(acc[i].w) << 16);
            *(uint2*)(h16 + (size_t)n * 32 + tx * 2) = pk;
        }
    }
}

// ---------------- radix partition: edges -> cells[bucket][block][CAP], LDS cursors only ----------------
__global__ __launch_bounds__(256) void k_partition(const int* __restrict__ ei,
                                                   unsigned* __restrict__ cells,
                                                   int* __restrict__ cntg,
                                                   uint2* __restrict__ spill,
                                                   int* __restrict__ spillCount,
                                                   int nEdges, int nNodes, int nBuckets) {
    __shared__ int curs[MAXBUCKETS];
    __shared__ int is64s;
    int tid = threadIdx.x;
    for (int i = tid; i < nBuckets; i += 256) curs[i] = 0;
    if (tid == 0) {
        int v = 1;
#pragma unroll
        for (int j = 0; j < 16; ++j)
            if (ei[2 * j + 1] != 0) v = 0;
        is64s = v;
    }
    __syncthreads();
    int is64 = is64s;

    int chunk = (nEdges + PBLOCKS - 1) / PBLOCKS;
    int e0 = blockIdx.x * chunk;
    int e1 = min(e0 + chunk, nEdges);
    for (int e = e0 + tid; e < e1; e += 256) {
        int src, dst;
        if (is64) {
            src = ((const int2*)ei)[e].x;
            dst = ((const int2*)ei)[nEdges + e].x;
        } else {
            src = ei[e];
            dst = ei[nEdges + e];
        }
        if ((unsigned)src >= (unsigned)nNodes) src = 0;
        if ((unsigned)dst >= (unsigned)nNodes) dst = 0;
        int bucket = dst >> 6;
        int rank = atomicAdd(&curs[bucket], 1);   // LDS atomic — cheap
        if (rank < CAP) {
            cells[((size_t)bucket * PBLOCKS + blockIdx.x) * CAP + rank] =
                (unsigned)src | ((unsigned)(dst & 63) << 16);
        } else {
            int sp = atomicAdd(spillCount, 1);    // ~never
            if (sp < nEdges) spill[sp] = make_uint2((unsigned)src, (unsigned)dst);
        }
    }
    __syncthreads();
    for (int i = tid; i < nBuckets; i += 256)
        cntg[(size_t)i * PBLOCKS + blockIdx.x] = min(curs[i], CAP);
}

// ---------------- aggregate: one block per bucket; LDS queue + LDS fp32 accumulator ----------------
__global__ __launch_bounds__(256) void k_aggregate(const unsigned* __restrict__ cells,
                                                   const int* __restrict__ cntg,
                                                   const unsigned* __restrict__ h16,
                                                   const float* __restrict__ bias,
                                                   float* __restrict__ out, int nNodes) {
    __shared__ float acc[NPB * OUT_CH];        // 16 KB
    __shared__ unsigned queue[PBLOCKS * CAP];  // 32 KB
    __shared__ int cnts[PBLOCKS];              // 2 KB
    __shared__ int qcnt;

    int tid = threadIdx.x;
    int bucket = blockIdx.x;
    for (int i = tid; i < NPB * OUT_CH; i += 256) acc[i] = 0.f;
    if (tid == 0) qcnt = 0;
    for (int i = tid; i < PBLOCKS; i += 256)
        cnts[i] = cntg[(size_t)bucket * PBLOCKS + i];
    __syncthreads();

    // compact valid recs into LDS queue
    const unsigned* cbase = cells + (size_t)bucket * PBLOCKS * CAP;
    for (int j = tid; j < PBLOCKS * CAP; j += 256) {
        if ((j & (CAP - 1)) < cnts[j >> 4]) {
            unsigned rec = cbase[j];
            int pos = atomicAdd(&qcnt, 1);
            queue[pos] = rec;
        }
    }
    __syncthreads();

    int n = qcnt;
    int grp = tid >> 5;   // 8 edge-groups
    int cp  = tid & 31;   // channel pair (bf16x2)
    int i = grp;
    for (; i + 8 < n; i += 16) {  // unroll 2: two h-loads in flight
        unsigned r0 = queue[i];
        unsigned r1 = queue[i + 8];
        unsigned v0 = h16[(size_t)(r0 & 0xFFFFu) * 32 + cp];
        unsigned v1 = h16[(size_t)(r1 & 0xFFFFu) * 32 + cp];
        int d0 = (int)(r0 >> 16) * OUT_CH + cp * 2;
        int d1 = (int)(r1 >> 16) * OUT_CH + cp * 2;
        atomicAdd(&acc[d0],     __uint_as_float(v0 << 16));
        atomicAdd(&acc[d0 + 1], __uint_as_float(v0 & 0xFFFF0000u));
        atomicAdd(&acc[d1],     __uint_as_float(v1 << 16));
        atomicAdd(&acc[d1 + 1], __uint_as_float(v1 & 0xFFFF0000u));
    }
    if (i < n) {
        unsigned r0 = queue[i];
        unsigned v0 = h16[(size_t)(r0 & 0xFFFFu) * 32 + cp];
        int d0 = (int)(r0 >> 16) * OUT_CH + cp * 2;
        atomicAdd(&acc[d0],     __uint_as_float(v0 << 16));
        atomicAdd(&acc[d0 + 1], __uint_as_float(v0 & 0xFFFF0000u));
    }
    __syncthreads();

    // epilogue: bias + coalesced out write
    int nodeBase = bucket * NPB;
    for (int j = tid; j < NPB * OUT_CH / 4; j += 256) {
        int row = j >> 4;
        int node = nodeBase + row;
        if (node >= nNodes) continue;
        int c4 = (j & 15) * 4;
        float4 a = *(float4*)(acc + row * OUT_CH + c4);
        float4 bv = *(const float4*)(bias + c4);
        a.x += bv.x; a.y += bv.y; a.z += bv.z; a.w += bv.w;
        *(float4*)(out + (size_t)node * OUT_CH + c4) = a;
    }
}

// ---------------- spill fixup (normally 0 iterations) ----------------
__global__ __launch_bounds__(256) void k_spill(const uint2* __restrict__ spill,
                                               const int* __restrict__ spillCount,
                                               const unsigned* __restrict__ h16,
                                               float* __restrict__ out, int nEdges) {
    int n = *spillCount;
    if (n > nEdges) n = nEdges;
    long long total = (long long)n * 32;
    for (long long t = blockIdx.x * 256 + threadIdx.x; t < total; t += (long long)gridDim.x * 256) {
        int e = (int)(t >> 5);
        int cp = (int)(t & 31);
        uint2 sd = spill[e];
        unsigned v = h16[(size_t)sd.x * 32 + cp];
        float* o = out + (size_t)sd.y * OUT_CH + cp * 2;
        unsafeAtomicAdd(o + 0, __uint_as_float(v << 16));
        unsafeAtomicAdd(o + 1, __uint_as_float(v & 0xFFFF0000u));
    }
}

extern "C" void kernel_launch(void* const* d_in, const int* in_sizes, int n_in,
                              void* d_out, int out_size, void* d_ws, size_t ws_size,
                              hipStream_t stream) {
    const float* x    = (const float*)d_in[0];
    const int*   ei   = (const int*)d_in[1];
    const float* W    = (const float*)d_in[2];
    const float* bias = (const float*)d_in[3];
    float* out = (float*)d_out;

    int nNodes = in_sizes[0] / IN_CH;   // 50000
    int nEdges = in_sizes[1] / 2;       // 800000
    int nBuckets = (nNodes + NPB - 1) / NPB;  // 782

    char* p = (char*)d_ws;
    auto alloc = [&](size_t bytes) {
        char* r = p;
        p += (bytes + 255) & ~(size_t)255;
        return r;
    };
    unsigned* h16        = (unsigned*)alloc((size_t)nNodes * 32 * sizeof(unsigned));            // 6.4 MB
    unsigned* cells      = (unsigned*)alloc((size_t)nBuckets * PBLOCKS * CAP * sizeof(unsigned)); // 25.6 MB
    int*      cntg       = (int*)alloc((size_t)nBuckets * PBLOCKS * sizeof(int));               // 1.6 MB
    uint2*    spill      = (uint2*)alloc((size_t)nEdges * sizeof(uint2));                       // 6.4 MB
    int*      spillCount = (int*)alloc(sizeof(int));

    hipMemsetAsync(spillCount, 0, sizeof(int), stream);
    k_gemm<<<(nNodes + TN - 1) / TN, 256, 0, stream>>>(x, W, h16, nNodes);
    k_partition<<<PBLOCKS, 256, 0, stream>>>(ei, cells, cntg, spill, spillCount, nEdges, nNodes, nBuckets);
    k_aggregate<<<nBuckets, 256, 0, stream>>>(cells, cntg, h16, bias, out, nNodes);
    k_spill<<<64, 256, 0, stream>>>(spill, spillCount, h16, out, nEdges);
}

// Round 9
// 158.806 us; speedup vs baseline: 2.9257x; 2.9257x over previous
//
#include <hip/hip_runtime.h>

#define IN_CH 128
#define OUT_CH 64
#define TN 64            // nodes per gemm block
#define XS_STRIDE 132
#define WS_STRIDE 129

#define PBLOCKS 512      // partition grid
#define NB 800           // bucket capacity in partA LDS (bucket = dst>>6); supports nNodes<=51200 fast path
#define CAPA 12          // recs per (block,bucket) cell; lambda=2 -> P(overflow)~1e-7/cell
#define DCAP 64          // per-node slot capacity; deg ~ Poisson(16) -> P(>64) ~ 0

// fp32 -> bf16 (RNE)
__device__ __forceinline__ unsigned f2bf(float f) {
    unsigned u = __float_as_uint(f);
    return (u + 0x7FFFu + ((u >> 16) & 1u)) >> 16;
}

__device__ __forceinline__ void fma4(float4& acc, float s, const float4& wv) {
    acc.x += s * wv.x;
    acc.y += s * wv.y;
    acc.z += s * wv.z;
    acc.w += s * wv.w;
}

// ---------------- h = x @ W^T, h stored as bf16 pairs ----------------
__global__ __launch_bounds__(256) void k_gemm(const float* __restrict__ x,
                                              const float* __restrict__ W,
                                              unsigned* __restrict__ h16,  // [node][32] bf16x2
                                              int nNodes) {
    __shared__ float smem[TN * XS_STRIDE + IN_CH * OUT_CH];
    float* u  = smem;
    float* wt = smem + TN * XS_STRIDE;

    int tid = threadIdx.x;
    int nodeBase = blockIdx.x * TN;

    {
        const float4* W4 = (const float4*)W;
        for (int i = tid; i < IN_CH * OUT_CH / 4; i += 256) {
            float4 v = W4[i];
            int o = i >> 5;
            int k = (i & 31) * 4;
            float* d = u + o * WS_STRIDE + k;
            d[0] = v.x; d[1] = v.y; d[2] = v.z; d[3] = v.w;
        }
    }
    __syncthreads();
    {
        int o = tid & 63;
        int k0 = (tid >> 6) * 32;
#pragma unroll 8
        for (int k = k0; k < k0 + 32; ++k)
            wt[k * OUT_CH + o] = u[o * WS_STRIDE + k];
    }
    __syncthreads();
    {
        int remRows = nNodes - nodeBase;
        if (remRows > TN) remRows = TN;
        const float4* X4 = (const float4*)(x + (size_t)nodeBase * IN_CH);
        for (int i = tid; i < TN * IN_CH / 4; i += 256) {
            int r = i >> 5;
            int k = (i & 31) * 4;
            float4 v = make_float4(0.f, 0.f, 0.f, 0.f);
            if (r < remRows) v = X4[i];
            *(float4*)(u + r * XS_STRIDE + k) = v;
        }
    }
    __syncthreads();

    int tx = tid & 15;
    int ty = tid >> 4;

    float4 acc[4];
#pragma unroll
    for (int i = 0; i < 4; ++i) acc[i] = make_float4(0.f, 0.f, 0.f, 0.f);

    const float* wcol = wt + tx * 4;
#pragma unroll 4
    for (int k = 0; k < IN_CH; k += 4) {
        float4 w0 = *(const float4*)(wcol + (k + 0) * OUT_CH);
        float4 w1 = *(const float4*)(wcol + (k + 1) * OUT_CH);
        float4 w2 = *(const float4*)(wcol + (k + 2) * OUT_CH);
        float4 w3 = *(const float4*)(wcol + (k + 3) * OUT_CH);
#pragma unroll
        for (int i = 0; i < 4; ++i) {
            float4 a = *(const float4*)(u + (ty * 4 + i) * XS_STRIDE + k);
            fma4(acc[i], a.x, w0);
            fma4(acc[i], a.y, w1);
            fma4(acc[i], a.z, w2);
            fma4(acc[i], a.w, w3);
        }
    }

#pragma unroll
    for (int i = 0; i < 4; ++i) {
        int n = nodeBase + ty * 4 + i;
        if (n < nNodes) {
            uint2 pk;
            pk.x = f2bf(acc[i].x) | (f2bf(acc[i].y) << 16);
            pk.y = f2bf(acc[i].z) | (f2bf(acc[i].w) << 16);
            *(uint2*)(h16 + (size_t)n * 32 + tx * 2) = pk;
        }
    }
}

// ---------------- pass A: LDS-bin edge chunk by bucket, dump COALESCED ----------------
// cells layout: [blk][bucket][CAPA]  (block-contiguous => streaming writes)
__global__ __launch_bounds__(256) void k_partA(const int* __restrict__ ei,
                                               unsigned* __restrict__ cells,
                                               int* __restrict__ cntA,
                                               uint2* __restrict__ spill,
                                               int* __restrict__ spillCount,
                                               int nEdges, int nNodes) {
    __shared__ unsigned lists[NB * CAPA];   // 38.4 KB
    __shared__ int curs[NB];                // 3.2 KB
    __shared__ int is64s;
    int tid = threadIdx.x;
    for (int i = tid; i < NB; i += 256) curs[i] = 0;
    if (tid == 0) {
        int v = 1;
#pragma unroll
        for (int j = 0; j < 16; ++j)
            if (ei[2 * j + 1] != 0) v = 0;
        is64s = v;
    }
    __syncthreads();
    int is64 = is64s;

    int chunk = (nEdges + PBLOCKS - 1) / PBLOCKS;
    int e0 = blockIdx.x * chunk;
    int e1 = min(e0 + chunk, nEdges);
    for (int e = e0 + tid; e < e1; e += 256) {
        int src, dst;
        if (is64) {
            src = ((const int2*)ei)[e].x;
            dst = ((const int2*)ei)[nEdges + e].x;
        } else {
            src = ei[e];
            dst = ei[nEdges + e];
        }
        if ((unsigned)src >= (unsigned)nNodes) src = 0;
        if ((unsigned)dst >= (unsigned)nNodes) dst = 0;
        int bucket = dst >> 6;
        int rank = (bucket < NB) ? atomicAdd(&curs[bucket], 1) : CAPA;
        if (rank < CAPA) {
            lists[bucket * CAPA + rank] = (unsigned)src | ((unsigned)(dst & 63) << 16);
        } else {
            int sp = atomicAdd(spillCount, 1);   // ~0.04 events/run expected
            if (sp < nEdges) spill[sp] = make_uint2((unsigned)src, (unsigned)dst);
        }
    }
    __syncthreads();

    size_t base = (size_t)blockIdx.x * NB;
    for (int j = tid; j < NB * CAPA; j += 256)
        cells[base * CAPA + j] = lists[j];
    for (int i = tid; i < NB; i += 256)
        cntA[base + i] = min(curs[i], CAPA);
}

// ---------------- pass B: per-bucket, gather its 512 cells, bin by sub-node, dump slots ----------------
// NOTE: slots/cntB are PADDED to nBuckets*64 nodes — the 16 KB dump writes the full tile.
__global__ __launch_bounds__(256) void k_partB(const unsigned* __restrict__ cells,
                                               const int* __restrict__ cntA,
                                               int* __restrict__ slots,
                                               int* __restrict__ cntB,
                                               uint2* __restrict__ spill,
                                               int* __restrict__ spillCount,
                                               int nNodes, int nEdges) {
    __shared__ unsigned nl[64 * DCAP];   // 16 KB
    __shared__ int nc[64];
    int tid = threadIdx.x;
    int b = blockIdx.x;
    int nodeBase = b * 64;

    if (b >= NB) {   // beyond fast-path range: these dsts went to spill; just zero cnt
        for (int i = tid; i < 64; i += 256)
            cntB[nodeBase + i] = 0;
        return;
    }

    if (tid < 64) nc[tid] = 0;
    __syncthreads();

    for (int blk = tid; blk < PBLOCKS; blk += 256) {
        int c = cntA[(size_t)blk * NB + b];
        const unsigned* cb = cells + ((size_t)blk * NB + b) * CAPA;
        // (blk*NB+b)*CAPA*4 bytes is a multiple of 48 -> 16B-aligned: uint4 ok
        uint4 w0 = *(const uint4*)(cb + 0);
        uint4 w1 = *(const uint4*)(cb + 4);
        uint4 w2 = *(const uint4*)(cb + 8);
        unsigned w[CAPA] = {w0.x, w0.y, w0.z, w0.w, w1.x, w1.y, w1.z, w1.w, w2.x, w2.y, w2.z, w2.w};
#pragma unroll
        for (int r = 0; r < CAPA; ++r) {
            if (r < c) {
                unsigned rec = w[r];
                int sub = (int)(rec >> 16);
                int rank = atomicAdd(&nc[sub], 1);
                if (rank < DCAP) {
                    nl[sub * DCAP + rank] = rec & 0xFFFFu;
                } else {
                    int sp = atomicAdd(spillCount, 1);
                    if (sp < nEdges) spill[sp] = make_uint2(rec & 0xFFFFu, (unsigned)(nodeBase + sub));
                }
            }
        }
    }
    __syncthreads();

    // contiguous 16 KB dump into the PADDED slots tile
    for (int j = tid; j < 64 * DCAP; j += 256)
        slots[(size_t)nodeBase * DCAP + j] = (int)nl[j];
    for (int i = tid; i < 64; i += 256)
        cntB[nodeBase + i] = min(nc[i], DCAP);
}

// ---------------- gather-reduce: one wave per node ----------------
__global__ __launch_bounds__(256) void k_gather(const int* __restrict__ cnt,
                                                const int* __restrict__ slots,
                                                const unsigned* __restrict__ h16,
                                                const float* __restrict__ bias,
                                                float* __restrict__ out, int nNodes) {
    int tid = blockIdx.x * 256 + threadIdx.x;
    int node = tid >> 6;
    if (node >= nNodes) return;
    int lane = tid & 63;
    int half = lane >> 5;
    int cp   = lane & 31;

    int d = cnt[node];
    if (d < 0) d = 0;
    if (d > DCAP) d = DCAP;
    int b = node * DCAP;
    int e = b + d;

    float2 acc = {0.f, 0.f};
    int i = b + half;
    for (; i + 2 < e; i += 4) {
        int s0 = slots[i];
        int s1 = slots[i + 2];
        unsigned v0 = h16[(size_t)s0 * 32 + cp];
        unsigned v1 = h16[(size_t)s1 * 32 + cp];
        acc.x += __uint_as_float(v0 << 16);
        acc.y += __uint_as_float(v0 & 0xFFFF0000u);
        acc.x += __uint_as_float(v1 << 16);
        acc.y += __uint_as_float(v1 & 0xFFFF0000u);
    }
    if (i < e) {
        int s = slots[i];
        unsigned v = h16[(size_t)s * 32 + cp];
        acc.x += __uint_as_float(v << 16);
        acc.y += __uint_as_float(v & 0xFFFF0000u);
    }

    acc.x += __shfl_down(acc.x, 32, 64);
    acc.y += __shfl_down(acc.y, 32, 64);
    if (half == 0) {
        float2 bv = *(const float2*)(bias + cp * 2);
        float2 o;
        o.x = acc.x + bv.x;
        o.y = acc.y + bv.y;
        *(float2*)(out + (size_t)node * OUT_CH + cp * 2) = o;
    }
}

// ---------------- spill fixup (normally ~0 iterations) ----------------
__global__ __launch_bounds__(256) void k_spill(const uint2* __restrict__ spill,
                                               const int* __restrict__ spillCount,
                                               const unsigned* __restrict__ h16,
                                               float* __restrict__ out, int nEdges) {
    int n = *spillCount;
    if (n > nEdges) n = nEdges;
    long long total = (long long)n * 32;
    for (long long t = blockIdx.x * 256 + threadIdx.x; t < total; t += (long long)gridDim.x * 256) {
        int e = (int)(t >> 5);
        int cp = (int)(t & 31);
        uint2 sd = spill[e];
        unsigned v = h16[(size_t)sd.x * 32 + cp];
        float* o = out + (size_t)sd.y * OUT_CH + cp * 2;
        unsafeAtomicAdd(o + 0, __uint_as_float(v << 16));
        unsafeAtomicAdd(o + 1, __uint_as_float(v & 0xFFFF0000u));
    }
}

extern "C" void kernel_launch(void* const* d_in, const int* in_sizes, int n_in,
                              void* d_out, int out_size, void* d_ws, size_t ws_size,
                              hipStream_t stream) {
    const float* x    = (const float*)d_in[0];
    const int*   ei   = (const int*)d_in[1];
    const float* W    = (const float*)d_in[2];
    const float* bias = (const float*)d_in[3];
    float* out = (float*)d_out;

    int nNodes = in_sizes[0] / IN_CH;   // 50000
    int nEdges = in_sizes[1] / 2;       // 800000
    int realBuckets = (nNodes + 63) / 64;   // 782
    int padNodes = realBuckets * 64;        // 50048 — dump granularity

    char* p = (char*)d_ws;
    auto alloc = [&](size_t bytes) {
        char* r = p;
        p += (bytes + 255) & ~(size_t)255;
        return r;
    };
    unsigned* h16        = (unsigned*)alloc((size_t)nNodes * 32 * sizeof(unsigned));         // 6.4 MB
    unsigned* cells      = (unsigned*)alloc((size_t)PBLOCKS * NB * CAPA * sizeof(unsigned)); // 19.7 MB
    int*      cntA       = (int*)alloc((size_t)PBLOCKS * NB * sizeof(int));                  // 1.6 MB
    int*      slots      = (int*)alloc((size_t)padNodes * DCAP * sizeof(int));               // 12.8 MB (padded!)
    int*      cntB       = (int*)alloc((size_t)padNodes * sizeof(int));                      // padded
    uint2*    spill      = (uint2*)alloc((size_t)nEdges * sizeof(uint2));                    // 6.4 MB
    int*      spillCount = (int*)alloc(sizeof(int));

    hipMemsetAsync(spillCount, 0, sizeof(int), stream);
    k_gemm<<<(nNodes + TN - 1) / TN, 256, 0, stream>>>(x, W, h16, nNodes);
    k_partA<<<PBLOCKS, 256, 0, stream>>>(ei, cells, cntA, spill, spillCount, nEdges, nNodes);
    k_partB<<<realBuckets, 256, 0, stream>>>(cells, cntA, slots, cntB, spill, spillCount, nNodes, nEdges);
    k_gather<<<(nNodes * OUT_CH + 255) / 256, 256, 0, stream>>>(cntB, slots, h16, bias, out, nNodes);
    k_spill<<<64, 256, 0, stream>>>(spill, spillCount, h16, out, nEdges);
}

// Round 11
// 145.206 us; speedup vs baseline: 3.1997x; 1.0937x over previous
//
#include <hip/hip_runtime.h>

#define IN_CH 128
#define OUT_CH 64
#define TN 64            // nodes per gemm block
#define XS_STRIDE 132
#define WS_STRIDE 129

#define PBLOCKS 512      // partition grid
#define NB 800           // partA bucket count (bucket = dst>>6); fast path for nNodes<=51200
#define CAPA 16          // recs per (block,bucket) cell: 64 B = one cache line, pow2
#define DCAP 64          // per-node slot capacity; deg ~ Poisson(16) -> P(>64) ~ 0

// fp32 -> bf16 (RNE)
__device__ __forceinline__ unsigned f2bf(float f) {
    unsigned u = __float_as_uint(f);
    return (u + 0x7FFFu + ((u >> 16) & 1u)) >> 16;
}

__device__ __forceinline__ void fma4(float4& acc, float s, const float4& wv) {
    acc.x += s * wv.x;
    acc.y += s * wv.y;
    acc.z += s * wv.z;
    acc.w += s * wv.w;
}

// ---------------- h = x @ W^T, h stored as bf16 pairs; also resets spillCount ----------------
__global__ __launch_bounds__(256) void k_gemm(const float* __restrict__ x,
                                              const float* __restrict__ W,
                                              unsigned* __restrict__ h16,  // [node][32] bf16x2
                                              int* __restrict__ spillCount,
                                              int nNodes) {
    __shared__ float smem[TN * XS_STRIDE + IN_CH * OUT_CH];
    float* u  = smem;
    float* wt = smem + TN * XS_STRIDE;

    int tid = threadIdx.x;
    int nodeBase = blockIdx.x * TN;
    if (blockIdx.x == 0 && tid == 0) *spillCount = 0;   // stream-ordered before partA

    {
        const float4* W4 = (const float4*)W;
        for (int i = tid; i < IN_CH * OUT_CH / 4; i += 256) {
            float4 v = W4[i];
            int o = i >> 5;
            int k = (i & 31) * 4;
            float* d = u + o * WS_STRIDE + k;
            d[0] = v.x; d[1] = v.y; d[2] = v.z; d[3] = v.w;
        }
    }
    __syncthreads();
    {
        int o = tid & 63;
        int k0 = (tid >> 6) * 32;
#pragma unroll 8
        for (int k = k0; k < k0 + 32; ++k)
            wt[k * OUT_CH + o] = u[o * WS_STRIDE + k];
    }
    __syncthreads();
    {
        int remRows = nNodes - nodeBase;
        if (remRows > TN) remRows = TN;
        const float4* X4 = (const float4*)(x + (size_t)nodeBase * IN_CH);
        for (int i = tid; i < TN * IN_CH / 4; i += 256) {
            int r = i >> 5;
            int k = (i & 31) * 4;
            float4 v = make_float4(0.f, 0.f, 0.f, 0.f);
            if (r < remRows) v = X4[i];
            *(float4*)(u + r * XS_STRIDE + k) = v;
        }
    }
    __syncthreads();

    int tx = tid & 15;
    int ty = tid >> 4;

    float4 acc[4];
#pragma unroll
    for (int i = 0; i < 4; ++i) acc[i] = make_float4(0.f, 0.f, 0.f, 0.f);

    const float* wcol = wt + tx * 4;
#pragma unroll 4
    for (int k = 0; k < IN_CH; k += 4) {
        float4 w0 = *(const float4*)(wcol + (k + 0) * OUT_CH);
        float4 w1 = *(const float4*)(wcol + (k + 1) * OUT_CH);
        float4 w2 = *(const float4*)(wcol + (k + 2) * OUT_CH);
        float4 w3 = *(const float4*)(wcol + (k + 3) * OUT_CH);
#pragma unroll
        for (int i = 0; i < 4; ++i) {
            float4 a = *(const float4*)(u + (ty * 4 + i) * XS_STRIDE + k);
            fma4(acc[i], a.x, w0);
            fma4(acc[i], a.y, w1);
            fma4(acc[i], a.z, w2);
            fma4(acc[i], a.w, w3);
        }
    }

#pragma unroll
    for (int i = 0; i < 4; ++i) {
        int n = nodeBase + ty * 4 + i;
        if (n < nNodes) {
            uint2 pk;
            pk.x = f2bf(acc[i].x) | (f2bf(acc[i].y) << 16);
            pk.y = f2bf(acc[i].z) | (f2bf(acc[i].w) << 16);
            *(uint2*)(h16 + (size_t)n * 32 + tx * 2) = pk;
        }
    }
}

// ---------------- pass A: LDS-bin edge chunk by bucket, dump COALESCED (uint4) ----------------
__global__ __launch_bounds__(256) void k_partA(const int* __restrict__ ei,
                                               unsigned* __restrict__ cells,
                                               int* __restrict__ cntA,
                                               uint2* __restrict__ spill,
                                               int* __restrict__ spillCount,
                                               int nEdges, int nNodes) {
    __shared__ unsigned lists[NB * CAPA];   // 51.2 KB
    __shared__ int curs[NB];                // 3.2 KB
    __shared__ int is64s;
    int tid = threadIdx.x;
    for (int i = tid; i < NB; i += 256) curs[i] = 0;
    if (tid == 0) {
        int v = 1;
#pragma unroll
        for (int j = 0; j < 16; ++j)
            if (ei[2 * j + 1] != 0) v = 0;
        is64s = v;
    }
    __syncthreads();
    int is64 = is64s;

    int chunk = (nEdges + PBLOCKS - 1) / PBLOCKS;
    int e0 = blockIdx.x * chunk;
    int e1 = min(e0 + chunk, nEdges);
    for (int e = e0 + tid; e < e1; e += 256) {
        int src, dst;
        if (is64) {
            src = ((const int2*)ei)[e].x;
            dst = ((const int2*)ei)[nEdges + e].x;
        } else {
            src = ei[e];
            dst = ei[nEdges + e];
        }
        if ((unsigned)src >= (unsigned)nNodes) src = 0;
        if ((unsigned)dst >= (unsigned)nNodes) dst = 0;
        int bucket = dst >> 6;
        int rank = (bucket < NB) ? atomicAdd(&curs[bucket], 1) : CAPA;
        if (rank < CAPA) {
            lists[bucket * CAPA + rank] = (unsigned)src | ((unsigned)(dst & 63) << 16);
        } else {
            int sp = atomicAdd(spillCount, 1);   // ~never (lambda~2 vs CAP 16)
            if (sp < nEdges) spill[sp] = make_uint2((unsigned)src, (unsigned)dst);
        }
    }
    __syncthreads();

    size_t base = (size_t)blockIdx.x * NB;
    uint4* cells4 = (uint4*)(cells + base * CAPA);
    for (int j = tid; j < NB * CAPA / 4; j += 256)
        cells4[j] = *(const uint4*)(lists + 4 * j);
    for (int i = tid; i < NB; i += 256)
        cntA[base + i] = min(curs[i], CAPA);
}

// ---------------- pass B: per-bucket, gather 512 aligned cells, bin by sub-node, dump ----------------
__global__ __launch_bounds__(256) void k_partB(const unsigned* __restrict__ cells,
                                               const int* __restrict__ cntA,
                                               int* __restrict__ slots,
                                               int* __restrict__ cntB,
                                               uint2* __restrict__ spill,
                                               int* __restrict__ spillCount,
                                               int nNodes, int nEdges) {
    __shared__ unsigned nl[64 * DCAP];   // 16 KB
    __shared__ int nc[64];
    int tid = threadIdx.x;
    int b = blockIdx.x;
    int nodeBase = b * 64;

    if (b >= NB) {
        for (int i = tid; i < 64; i += 256)
            cntB[nodeBase + i] = 0;
        return;
    }

    if (tid < 64) nc[tid] = 0;
    __syncthreads();

    for (int blk = tid; blk < PBLOCKS; blk += 256) {
        int c = cntA[(size_t)blk * NB + b];
        const unsigned* cb = cells + ((size_t)blk * NB + b) * CAPA;  // 64-B aligned
        uint4 w0 = *(const uint4*)(cb + 0);
        uint4 w1 = *(const uint4*)(cb + 4);
        uint4 w2 = *(const uint4*)(cb + 8);
        uint4 w3 = *(const uint4*)(cb + 12);
        unsigned w[CAPA] = {w0.x, w0.y, w0.z, w0.w, w1.x, w1.y, w1.z, w1.w,
                            w2.x, w2.y, w2.z, w2.w, w3.x, w3.y, w3.z, w3.w};
#pragma unroll
        for (int r = 0; r < CAPA; ++r) {
            if (r < c) {
                unsigned rec = w[r];
                int sub = (int)(rec >> 16);
                int rank = atomicAdd(&nc[sub], 1);
                if (rank < DCAP) {
                    nl[sub * DCAP + rank] = rec & 0xFFFFu;
                } else {
                    int sp = atomicAdd(spillCount, 1);
                    if (sp < nEdges) spill[sp] = make_uint2(rec & 0xFFFFu, (unsigned)(nodeBase + sub));
                }
            }
        }
    }
    __syncthreads();

    uint4* s4 = (uint4*)(slots + (size_t)nodeBase * DCAP);
    for (int j = tid; j < 64 * DCAP / 4; j += 256)
        s4[j] = *(const uint4*)(nl + 4 * j);
    for (int i = tid; i < 64; i += 256)
        cntB[nodeBase + i] = min(nc[i], DCAP);
}

// ---------------- gather-reduce: one wave per node; slots preloaded, CONVERGENT shfl ----------------
// Loop bound jend = round-up-even(d): both halves (j=0 vs j=1 start) get identical trip
// counts in main and remainder loops, so the wave never diverges and every __shfl runs
// with full exec (divergent bpermute reads from inactive lanes = undefined -> round-10 bug).
// Tail element j==d (only when d odd) is zeroed branchlessly before accumulation.
__global__ __launch_bounds__(256) void k_gather(const int* __restrict__ cnt,
                                                const int* __restrict__ slots,
                                                const unsigned* __restrict__ h16,
                                                const float* __restrict__ bias,
                                                float* __restrict__ out, int nNodes) {
    int tid = blockIdx.x * 256 + threadIdx.x;
    int node = tid >> 6;
    if (node >= nNodes) return;
    int lane = tid & 63;
    int half = lane >> 5;
    int cp   = lane & 31;

    int d = cnt[node];
    if (d < 0) d = 0;
    if (d > DCAP) d = DCAP;
    int jend = (d + 1) & ~1;   // even upper bound, uniform across wave

    // one coalesced 256-B read grabs ALL this node's slots (lane i -> slot i)
    int myslot = (lane < d) ? slots[node * DCAP + lane] : 0;

    float2 acc = {0.f, 0.f};
    int j = half;
    for (; j + 6 < jend; j += 8) {   // condition identical for both halves (jend even)
        int s0 = __shfl(myslot, j, 64);
        int s1 = __shfl(myslot, j + 2, 64);
        int s2 = __shfl(myslot, j + 4, 64);
        int s3 = __shfl(myslot, j + 6, 64);
        unsigned v0 = h16[(size_t)s0 * 32 + cp];
        unsigned v1 = h16[(size_t)s1 * 32 + cp];
        unsigned v2 = h16[(size_t)s2 * 32 + cp];
        unsigned v3 = h16[(size_t)s3 * 32 + cp];
        if (j + 6 >= d) v3 = 0;      // only possible tail element in main loop
        acc.x += __uint_as_float(v0 << 16);
        acc.y += __uint_as_float(v0 & 0xFFFF0000u);
        acc.x += __uint_as_float(v1 << 16);
        acc.y += __uint_as_float(v1 & 0xFFFF0000u);
        acc.x += __uint_as_float(v2 << 16);
        acc.y += __uint_as_float(v2 & 0xFFFF0000u);
        acc.x += __uint_as_float(v3 << 16);
        acc.y += __uint_as_float(v3 & 0xFFFF0000u);
    }
    for (; j < jend; j += 2) {       // condition identical for both halves (jend even)
        int s = __shfl(myslot, j, 64);
        unsigned v = h16[(size_t)s * 32 + cp];
        if (j >= d) v = 0;
        acc.x += __uint_as_float(v << 16);
        acc.y += __uint_as_float(v & 0xFFFF0000u);
    }

    acc.x += __shfl_down(acc.x, 32, 64);
    acc.y += __shfl_down(acc.y, 32, 64);
    if (half == 0) {
        float2 bv = *(const float2*)(bias + cp * 2);
        float2 o;
        o.x = acc.x + bv.x;
        o.y = acc.y + bv.y;
        *(float2*)(out + (size_t)node * OUT_CH + cp * 2) = o;
    }
}

// ---------------- spill fixup (normally 0 iterations) ----------------
__global__ __launch_bounds__(256) void k_spill(const uint2* __restrict__ spill,
                                               const int* __restrict__ spillCount,
                                               const unsigned* __restrict__ h16,
                                               float* __restrict__ out, int nEdges) {
    int n = *spillCount;
    if (n > nEdges) n = nEdges;
    long long total = (long long)n * 32;
    for (long long t = blockIdx.x * 256 + threadIdx.x; t < total; t += (long long)gridDim.x * 256) {
        int e = (int)(t >> 5);
        int cp = (int)(t & 31);
        uint2 sd = spill[e];
        unsigned v = h16[(size_t)sd.x * 32 + cp];
        float* o = out + (size_t)sd.y * OUT_CH + cp * 2;
        unsafeAtomicAdd(o + 0, __uint_as_float(v << 16));
        unsafeAtomicAdd(o + 1, __uint_as_float(v & 0xFFFF0000u));
    }
}

extern "C" void kernel_launch(void* const* d_in, const int* in_sizes, int n_in,
                              void* d_out, int out_size, void* d_ws, size_t ws_size,
                              hipStream_t stream) {
    const float* x    = (const float*)d_in[0];
    const int*   ei   = (const int*)d_in[1];
    const float* W    = (const float*)d_in[2];
    const float* bias = (const float*)d_in[3];
    float* out = (float*)d_out;

    int nNodes = in_sizes[0] / IN_CH;   // 50000
    int nEdges = in_sizes[1] / 2;       // 800000
    int realBuckets = (nNodes + 63) / 64;   // 782
    int padNodes = realBuckets * 64;        // 50048 — dump granularity

    char* p = (char*)d_ws;
    auto alloc = [&](size_t bytes) {
        char* r = p;
        p += (bytes + 255) & ~(size_t)255;
        return r;
    };
    unsigned* h16        = (unsigned*)alloc((size_t)nNodes * 32 * sizeof(unsigned));         // 6.4 MB
    unsigned* cells      = (unsigned*)alloc((size_t)PBLOCKS * NB * CAPA * sizeof(unsigned)); // 26.2 MB
    int*      cntA       = (int*)alloc((size_t)PBLOCKS * NB * sizeof(int));                  // 1.6 MB
    int*      slots      = (int*)alloc((size_t)padNodes * DCAP * sizeof(int));               // 12.8 MB (padded)
    int*      cntB       = (int*)alloc((size_t)padNodes * sizeof(int));                      // padded
    uint2*    spill      = (uint2*)alloc((size_t)nEdges * sizeof(uint2));                    // 6.4 MB
    int*      spillCount = (int*)alloc(sizeof(int));

    k_gemm<<<(nNodes + TN - 1) / TN, 256, 0, stream>>>(x, W, h16, spillCount, nNodes);
    k_partA<<<PBLOCKS, 256, 0, stream>>>(ei, cells, cntA, spill, spillCount, nEdges, nNodes);
    k_partB<<<realBuckets, 256, 0, stream>>>(cells, cntA, slots, cntB, spill, spillCount, nNodes, nEdges);
    k_gather<<<(nNodes * OUT_CH + 255) / 256, 256, 0, stream>>>(cntB, slots, h16, bias, out, nNodes);
    k_spill<<<64, 256, 0, stream>>>(spill, spillCount, h16, out, nEdges);
}

// Round 12
// 143.966 us; speedup vs baseline: 3.2273x; 1.0086x over previous
//
#include <hip/hip_runtime.h>

#define IN_CH 128
#define OUT_CH 64
#define TN 64            // nodes per gemm block
#define XS_STRIDE 132
#define WS_STRIDE 129

#define PBLOCKS 512      // partition grid
#define NB 800           // partA bucket count (bucket = dst>>6); fast path for nNodes<=51200
#define CAPA 8           // recs per (block,bucket) cell: 32 B, lambda~2 -> ~80 spills/run (k_spill)
#define DCAP 32          // per-node slot capacity; Poisson(16): P(>32)~1e-5 -> ~1 node spills

// fp32 -> bf16 (RNE)
__device__ __forceinline__ unsigned f2bf(float f) {
    unsigned u = __float_as_uint(f);
    return (u + 0x7FFFu + ((u >> 16) & 1u)) >> 16;
}

__device__ __forceinline__ void fma4(float4& acc, float s, const float4& wv) {
    acc.x += s * wv.x;
    acc.y += s * wv.y;
    acc.z += s * wv.z;
    acc.w += s * wv.w;
}

// ---------------- h = x @ W^T, h stored as bf16 pairs; also resets spillCount ----------------
__global__ __launch_bounds__(256) void k_gemm(const float* __restrict__ x,
                                              const float* __restrict__ W,
                                              unsigned* __restrict__ h16,  // [node][32] bf16x2
                                              int* __restrict__ spillCount,
                                              int nNodes) {
    __shared__ float smem[TN * XS_STRIDE + IN_CH * OUT_CH];
    float* u  = smem;
    float* wt = smem + TN * XS_STRIDE;

    int tid = threadIdx.x;
    int nodeBase = blockIdx.x * TN;
    if (blockIdx.x == 0 && tid == 0) *spillCount = 0;   // stream-ordered before partA

    {
        const float4* W4 = (const float4*)W;
        for (int i = tid; i < IN_CH * OUT_CH / 4; i += 256) {
            float4 v = W4[i];
            int o = i >> 5;
            int k = (i & 31) * 4;
            float* d = u + o * WS_STRIDE + k;
            d[0] = v.x; d[1] = v.y; d[2] = v.z; d[3] = v.w;
        }
    }
    __syncthreads();
    {
        int o = tid & 63;
        int k0 = (tid >> 6) * 32;
#pragma unroll 8
        for (int k = k0; k < k0 + 32; ++k)
            wt[k * OUT_CH + o] = u[o * WS_STRIDE + k];
    }
    __syncthreads();
    {
        int remRows = nNodes - nodeBase;
        if (remRows > TN) remRows = TN;
        const float4* X4 = (const float4*)(x + (size_t)nodeBase * IN_CH);
        for (int i = tid; i < TN * IN_CH / 4; i += 256) {
            int r = i >> 5;
            int k = (i & 31) * 4;
            float4 v = make_float4(0.f, 0.f, 0.f, 0.f);
            if (r < remRows) v = X4[i];
            *(float4*)(u + r * XS_STRIDE + k) = v;
        }
    }
    __syncthreads();

    int tx = tid & 15;
    int ty = tid >> 4;

    float4 acc[4];
#pragma unroll
    for (int i = 0; i < 4; ++i) acc[i] = make_float4(0.f, 0.f, 0.f, 0.f);

    const float* wcol = wt + tx * 4;
#pragma unroll 4
    for (int k = 0; k < IN_CH; k += 4) {
        float4 w0 = *(const float4*)(wcol + (k + 0) * OUT_CH);
        float4 w1 = *(const float4*)(wcol + (k + 1) * OUT_CH);
        float4 w2 = *(const float4*)(wcol + (k + 2) * OUT_CH);
        float4 w3 = *(const float4*)(wcol + (k + 3) * OUT_CH);
#pragma unroll
        for (int i = 0; i < 4; ++i) {
            float4 a = *(const float4*)(u + (ty * 4 + i) * XS_STRIDE + k);
            fma4(acc[i], a.x, w0);
            fma4(acc[i], a.y, w1);
            fma4(acc[i], a.z, w2);
            fma4(acc[i], a.w, w3);
        }
    }

#pragma unroll
    for (int i = 0; i < 4; ++i) {
        int n = nodeBase + ty * 4 + i;
        if (n < nNodes) {
            uint2 pk;
            pk.x = f2bf(acc[i].x) | (f2bf(acc[i].y) << 16);
            pk.y = f2bf(acc[i].z) | (f2bf(acc[i].w) << 16);
            *(uint2*)(h16 + (size_t)n * 32 + tx * 2) = pk;
        }
    }
}

// ---------------- pass A: LDS-bin edge chunk by bucket, dump COALESCED (uint4) ----------------
__global__ __launch_bounds__(256) void k_partA(const int* __restrict__ ei,
                                               unsigned* __restrict__ cells,
                                               int* __restrict__ cntA,
                                               uint2* __restrict__ spill,
                                               int* __restrict__ spillCount,
                                               int nEdges, int nNodes) {
    __shared__ unsigned lists[NB * CAPA];   // 25.6 KB
    __shared__ int curs[NB];                // 3.2 KB
    __shared__ int is64s;
    int tid = threadIdx.x;
    for (int i = tid; i < NB; i += 256) curs[i] = 0;
    if (tid == 0) {
        int v = 1;
#pragma unroll
        for (int j = 0; j < 16; ++j)
            if (ei[2 * j + 1] != 0) v = 0;
        is64s = v;
    }
    __syncthreads();
    int is64 = is64s;

    int chunk = (nEdges + PBLOCKS - 1) / PBLOCKS;
    int e0 = blockIdx.x * chunk;
    int e1 = min(e0 + chunk, nEdges);
    for (int e = e0 + tid; e < e1; e += 256) {
        int src, dst;
        if (is64) {
            src = ((const int2*)ei)[e].x;
            dst = ((const int2*)ei)[nEdges + e].x;
        } else {
            src = ei[e];
            dst = ei[nEdges + e];
        }
        if ((unsigned)src >= (unsigned)nNodes) src = 0;
        if ((unsigned)dst >= (unsigned)nNodes) dst = 0;
        int bucket = dst >> 6;
        int rank = (bucket < NB) ? atomicAdd(&curs[bucket], 1) : CAPA;
        if (rank < CAPA) {
            lists[bucket * CAPA + rank] = (unsigned)src | ((unsigned)(dst & 63) << 16);
        } else {
            int sp = atomicAdd(spillCount, 1);   // ~80 edges/run expected (lambda~2, CAP 8)
            if (sp < nEdges) spill[sp] = make_uint2((unsigned)src, (unsigned)dst);
        }
    }
    __syncthreads();

    size_t base = (size_t)blockIdx.x * NB;
    uint4* cells4 = (uint4*)(cells + base * CAPA);
    for (int j = tid; j < NB * CAPA / 4; j += 256)
        cells4[j] = *(const uint4*)(lists + 4 * j);
    for (int i = tid; i < NB; i += 256)
        cntA[base + i] = min(curs[i], CAPA);
}

// ---------------- pass B: per-bucket, gather 512 aligned 32-B cells, bin by sub-node, dump ----------------
__global__ __launch_bounds__(256) void k_partB(const unsigned* __restrict__ cells,
                                               const int* __restrict__ cntA,
                                               int* __restrict__ slots,
                                               int* __restrict__ cntB,
                                               uint2* __restrict__ spill,
                                               int* __restrict__ spillCount,
                                               int nNodes, int nEdges) {
    __shared__ unsigned nl[64 * DCAP];   // 8 KB
    __shared__ int nc[64];
    int tid = threadIdx.x;
    int b = blockIdx.x;
    int nodeBase = b * 64;

    if (b >= NB) {
        for (int i = tid; i < 64; i += 256)
            cntB[nodeBase + i] = 0;
        return;
    }

    if (tid < 64) nc[tid] = 0;
    __syncthreads();

    for (int blk = tid; blk < PBLOCKS; blk += 256) {
        int c = cntA[(size_t)blk * NB + b];
        const unsigned* cb = cells + ((size_t)blk * NB + b) * CAPA;  // 32-B aligned
        uint4 w0 = *(const uint4*)(cb + 0);
        uint4 w1 = *(const uint4*)(cb + 4);
        unsigned w[CAPA] = {w0.x, w0.y, w0.z, w0.w, w1.x, w1.y, w1.z, w1.w};
#pragma unroll
        for (int r = 0; r < CAPA; ++r) {
            if (r < c) {
                unsigned rec = w[r];
                int sub = (int)(rec >> 16);
                int rank = atomicAdd(&nc[sub], 1);
                if (rank < DCAP) {
                    nl[sub * DCAP + rank] = rec & 0xFFFFu;
                } else {
                    int sp = atomicAdd(spillCount, 1);   // ~1 node/run exceeds 32
                    if (sp < nEdges) spill[sp] = make_uint2(rec & 0xFFFFu, (unsigned)(nodeBase + sub));
                }
            }
        }
    }
    __syncthreads();

    uint4* s4 = (uint4*)(slots + (size_t)nodeBase * DCAP);
    for (int j = tid; j < 64 * DCAP / 4; j += 256)
        s4[j] = *(const uint4*)(nl + 4 * j);
    for (int i = tid; i < 64; i += 256)
        cntB[nodeBase + i] = min(nc[i], DCAP);
}

// ---------------- gather-reduce: one wave per node; slots preloaded, CONVERGENT shfl ----------------
// jend = round-up-even(d): identical trip counts for both halves -> no divergence around __shfl.
__global__ __launch_bounds__(256) void k_gather(const int* __restrict__ cnt,
                                                const int* __restrict__ slots,
                                                const unsigned* __restrict__ h16,
                                                const float* __restrict__ bias,
                                                float* __restrict__ out, int nNodes) {
    int tid = blockIdx.x * 256 + threadIdx.x;
    int node = tid >> 6;
    if (node >= nNodes) return;
    int lane = tid & 63;
    int half = lane >> 5;
    int cp   = lane & 31;

    int d = cnt[node];
    if (d < 0) d = 0;
    if (d > DCAP) d = DCAP;
    int jend = (d + 1) & ~1;   // even upper bound, uniform across wave

    // one coalesced 128-B read grabs ALL this node's slots (lane i -> slot i, d <= 32)
    int myslot = (lane < d) ? slots[node * DCAP + lane] : 0;

    float2 acc = {0.f, 0.f};
    int j = half;
    for (; j + 6 < jend; j += 8) {   // condition identical for both halves (jend even)
        int s0 = __shfl(myslot, j, 64);
        int s1 = __shfl(myslot, j + 2, 64);
        int s2 = __shfl(myslot, j + 4, 64);
        int s3 = __shfl(myslot, j + 6, 64);
        unsigned v0 = h16[(size_t)s0 * 32 + cp];
        unsigned v1 = h16[(size_t)s1 * 32 + cp];
        unsigned v2 = h16[(size_t)s2 * 32 + cp];
        unsigned v3 = h16[(size_t)s3 * 32 + cp];
        if (j + 6 >= d) v3 = 0;      // only possible tail element in main loop
        acc.x += __uint_as_float(v0 << 16);
        acc.y += __uint_as_float(v0 & 0xFFFF0000u);
        acc.x += __uint_as_float(v1 << 16);
        acc.y += __uint_as_float(v1 & 0xFFFF0000u);
        acc.x += __uint_as_float(v2 << 16);
        acc.y += __uint_as_float(v2 & 0xFFFF0000u);
        acc.x += __uint_as_float(v3 << 16);
        acc.y += __uint_as_float(v3 & 0xFFFF0000u);
    }
    for (; j < jend; j += 2) {       // condition identical for both halves (jend even)
        int s = __shfl(myslot, j, 64);
        unsigned v = h16[(size_t)s * 32 + cp];
        if (j >= d) v = 0;
        acc.x += __uint_as_float(v << 16);
        acc.y += __uint_as_float(v & 0xFFFF0000u);
    }

    acc.x += __shfl_down(acc.x, 32, 64);
    acc.y += __shfl_down(acc.y, 32, 64);
    if (half == 0) {
        float2 bv = *(const float2*)(bias + cp * 2);
        float2 o;
        o.x = acc.x + bv.x;
        o.y = acc.y + bv.y;
        *(float2*)(out + (size_t)node * OUT_CH + cp * 2) = o;
    }
}

// ---------------- spill fixup (~80 edges/run) ----------------
__global__ __launch_bounds__(256) void k_spill(const uint2* __restrict__ spill,
                                               const int* __restrict__ spillCount,
                                               const unsigned* __restrict__ h16,
                                               float* __restrict__ out, int nEdges) {
    int n = *spillCount;
    if (n > nEdges) n = nEdges;
    long long total = (long long)n * 32;
    for (long long t = blockIdx.x * 256 + threadIdx.x; t < total; t += (long long)gridDim.x * 256) {
        int e = (int)(t >> 5);
        int cp = (int)(t & 31);
        uint2 sd = spill[e];
        unsigned v = h16[(size_t)sd.x * 32 + cp];
        float* o = out + (size_t)sd.y * OUT_CH + cp * 2;
        unsafeAtomicAdd(o + 0, __uint_as_float(v << 16));
        unsafeAtomicAdd(o + 1, __uint_as_float(v & 0xFFFF0000u));
    }
}

extern "C" void kernel_launch(void* const* d_in, const int* in_sizes, int n_in,
                              void* d_out, int out_size, void* d_ws, size_t ws_size,
                              hipStream_t stream) {
    const float* x    = (const float*)d_in[0];
    const int*   ei   = (const int*)d_in[1];
    const float* W    = (const float*)d_in[2];
    const float* bias = (const float*)d_in[3];
    float* out = (float*)d_out;

    int nNodes = in_sizes[0] / IN_CH;   // 50000
    int nEdges = in_sizes[1] / 2;       // 800000
    int realBuckets = (nNodes + 63) / 64;   // 782
    int padNodes = realBuckets * 64;        // 50048 — dump granularity

    char* p = (char*)d_ws;
    auto alloc = [&](size_t bytes) {
        char* r = p;
        p += (bytes + 255) & ~(size_t)255;
        return r;
    };
    unsigned* h16        = (unsigned*)alloc((size_t)nNodes * 32 * sizeof(unsigned));         // 6.4 MB
    unsigned* cells      = (unsigned*)alloc((size_t)PBLOCKS * NB * CAPA * sizeof(unsigned)); // 13.1 MB
    int*      cntA       = (int*)alloc((size_t)PBLOCKS * NB * sizeof(int));                  // 1.6 MB
    int*      slots      = (int*)alloc((size_t)padNodes * DCAP * sizeof(int));               // 6.4 MB (padded)
    int*      cntB       = (int*)alloc((size_t)padNodes * sizeof(int));                      // padded
    uint2*    spill      = (uint2*)alloc((size_t)nEdges * sizeof(uint2));                    // 6.4 MB
    int*      spillCount = (int*)alloc(sizeof(int));

    k_gemm<<<(nNodes + TN - 1) / TN, 256, 0, stream>>>(x, W, h16, spillCount, nNodes);
    k_partA<<<PBLOCKS, 256, 0, stream>>>(ei, cells, cntA, spill, spillCount, nEdges, nNodes);
    k_partB<<<realBuckets, 256, 0, stream>>>(cells, cntA, slots, cntB, spill, spillCount, nNodes, nEdges);
    k_gather<<<(nNodes * OUT_CH + 255) / 256, 256, 0, stream>>>(cntB, slots, h16, bias, out, nNodes);
    k_spill<<<64, 256, 0, stream>>>(spill, spillCount, h16, out, nEdges);
}

// Round 13
// 138.270 us; speedup vs baseline: 3.3602x; 1.0412x over previous
//
#include <hip/hip_runtime.h>

#define IN_CH 128
#define OUT_CH 64
#define TN 64            // nodes per gemm block
#define XS_STRIDE 132
#define WS_STRIDE 129

#define PBLOCKS 512      // partition grid (partA role blocks)
#define NB 800           // partA bucket count (bucket = dst>>6); fast path for nNodes<=51200
#define CAPA 8           // recs per (block,bucket) cell: 32 B; lambda~2 -> ~80 spills/run
#define DCAP 32          // per-node slot capacity; Poisson(16): P(>32)~1e-5

// fp32 -> bf16 (RNE)
__device__ __forceinline__ unsigned f2bf(float f) {
    unsigned u = __float_as_uint(f);
    return (u + 0x7FFFu + ((u >> 16) & 1u)) >> 16;
}

__device__ __forceinline__ void fma4(float4& acc, float s, const float4& wv) {
    acc.x += s * wv.x;
    acc.y += s * wv.y;
    acc.z += s * wv.z;
    acc.w += s * wv.w;
}

// ---------------- fused: gemm role (blocks < gemmBlocks) | partA role (rest) ----------------
__global__ __launch_bounds__(256) void k_fusedA(const float* __restrict__ x,
                                                const float* __restrict__ W,
                                                unsigned* __restrict__ h16,   // [node][32] bf16x2
                                                const int* __restrict__ ei,
                                                unsigned* __restrict__ cells,
                                                int* __restrict__ cntA,
                                                uint2* __restrict__ spill,
                                                int* __restrict__ spillCount,
                                                int nNodes, int nEdges, int gemmBlocks) {
    __shared__ float smem[TN * XS_STRIDE + IN_CH * OUT_CH];  // 66.6 KB (partA uses a prefix)
    __shared__ int is64s;
    int tid = threadIdx.x;

    if (blockIdx.x >= gemmBlocks) {
        // ================= partA: LDS-bin edge chunk by bucket, dump coalesced =================
        unsigned* lists = (unsigned*)smem;            // NB*CAPA = 6400 u32 (25.6 KB)
        int* curs = (int*)smem + NB * CAPA;           // NB ints (3.2 KB)
        int pblk = blockIdx.x - gemmBlocks;
        for (int i = tid; i < NB; i += 256) curs[i] = 0;
        if (tid == 0) {
            int v = 1;
#pragma unroll
            for (int j = 0; j < 16; ++j)
                if (ei[2 * j + 1] != 0) v = 0;
            is64s = v;
        }
        __syncthreads();
        int is64 = is64s;

        int chunk = (nEdges + PBLOCKS - 1) / PBLOCKS;
        int e0 = pblk * chunk;
        int e1 = min(e0 + chunk, nEdges);
        for (int e = e0 + tid; e < e1; e += 256) {
            int src, dst;
            if (is64) {
                src = ((const int2*)ei)[e].x;
                dst = ((const int2*)ei)[nEdges + e].x;
            } else {
                src = ei[e];
                dst = ei[nEdges + e];
            }
            if ((unsigned)src >= (unsigned)nNodes) src = 0;
            if ((unsigned)dst >= (unsigned)nNodes) dst = 0;
            int bucket = dst >> 6;
            int rank = (bucket < NB) ? atomicAdd(&curs[bucket], 1) : CAPA;
            if (rank < CAPA) {
                lists[bucket * CAPA + rank] = (unsigned)src | ((unsigned)(dst & 63) << 16);
            } else {
                int sp = atomicAdd(spillCount, 1);
                if (sp < nEdges) spill[sp] = make_uint2((unsigned)src, (unsigned)dst);
            }
        }
        __syncthreads();

        size_t base = (size_t)pblk * NB;
        uint4* cells4 = (uint4*)(cells + base * CAPA);
        for (int j = tid; j < NB * CAPA / 4; j += 256)
            cells4[j] = *(const uint4*)(lists + 4 * j);
        for (int i = tid; i < NB; i += 256)
            cntA[base + i] = min(curs[i], CAPA);
        return;
    }

    // ================= gemm: h = x @ W^T, bf16 output =================
    float* u  = smem;
    float* wt = smem + TN * XS_STRIDE;
    int nodeBase = blockIdx.x * TN;

    {
        const float4* W4 = (const float4*)W;
        for (int i = tid; i < IN_CH * OUT_CH / 4; i += 256) {
            float4 v = W4[i];
            int o = i >> 5;
            int k = (i & 31) * 4;
            float* d = u + o * WS_STRIDE + k;
            d[0] = v.x; d[1] = v.y; d[2] = v.z; d[3] = v.w;
        }
    }
    __syncthreads();
    {
        int o = tid & 63;
        int k0 = (tid >> 6) * 32;
#pragma unroll 8
        for (int k = k0; k < k0 + 32; ++k)
            wt[k * OUT_CH + o] = u[o * WS_STRIDE + k];
    }
    __syncthreads();
    {
        int remRows = nNodes - nodeBase;
        if (remRows > TN) remRows = TN;
        const float4* X4 = (const float4*)(x + (size_t)nodeBase * IN_CH);
        for (int i = tid; i < TN * IN_CH / 4; i += 256) {
            int r = i >> 5;
            int k = (i & 31) * 4;
            float4 v = make_float4(0.f, 0.f, 0.f, 0.f);
            if (r < remRows) v = X4[i];
            *(float4*)(u + r * XS_STRIDE + k) = v;
        }
    }
    __syncthreads();

    int tx = tid & 15;
    int ty = tid >> 4;

    float4 acc[4];
#pragma unroll
    for (int i = 0; i < 4; ++i) acc[i] = make_float4(0.f, 0.f, 0.f, 0.f);

    const float* wcol = wt + tx * 4;
#pragma unroll 4
    for (int k = 0; k < IN_CH; k += 4) {
        float4 w0 = *(const float4*)(wcol + (k + 0) * OUT_CH);
        float4 w1 = *(const float4*)(wcol + (k + 1) * OUT_CH);
        float4 w2 = *(const float4*)(wcol + (k + 2) * OUT_CH);
        float4 w3 = *(const float4*)(wcol + (k + 3) * OUT_CH);
#pragma unroll
        for (int i = 0; i < 4; ++i) {
            float4 a = *(const float4*)(u + (ty * 4 + i) * XS_STRIDE + k);
            fma4(acc[i], a.x, w0);
            fma4(acc[i], a.y, w1);
            fma4(acc[i], a.z, w2);
            fma4(acc[i], a.w, w3);
        }
    }

#pragma unroll
    for (int i = 0; i < 4; ++i) {
        int n = nodeBase + ty * 4 + i;
        if (n < nNodes) {
            uint2 pk;
            pk.x = f2bf(acc[i].x) | (f2bf(acc[i].y) << 16);
            pk.y = f2bf(acc[i].z) | (f2bf(acc[i].w) << 16);
            *(uint2*)(h16 + (size_t)n * 32 + tx * 2) = pk;
        }
    }
}

// ---------------- fused: partB (bin bucket cells to LDS) + gather (from LDS) ----------------
// One 1024-thread block per bucket: 16 waves x 4 nodes = 64 nodes. Wave count equals the
// standalone gather (12512), so random-h16 latency hiding is preserved; the slots/cntB
// global round-trip and one launch bubble are eliminated.
__global__ __launch_bounds__(1024) void k_fusedB(const unsigned* __restrict__ cells,
                                                 const int* __restrict__ cntA,
                                                 const unsigned* __restrict__ h16,
                                                 const float* __restrict__ bias,
                                                 float* __restrict__ out,
                                                 uint2* __restrict__ spill,
                                                 int* __restrict__ spillCount,
                                                 int nNodes, int nEdges) {
    __shared__ unsigned nl[64 * DCAP];   // 8 KB
    __shared__ int nc[64];
    int tid = threadIdx.x;
    int b = blockIdx.x;
    int nodeBase = b * 64;

    if (tid < 64) nc[tid] = 0;
    __syncthreads();

    if (b < NB) {
        for (int blk = tid; blk < PBLOCKS; blk += 1024) {
            int c = cntA[(size_t)blk * NB + b];
            const unsigned* cb = cells + ((size_t)blk * NB + b) * CAPA;  // 32-B aligned
            uint4 w0 = *(const uint4*)(cb + 0);
            uint4 w1 = *(const uint4*)(cb + 4);
            unsigned w[CAPA] = {w0.x, w0.y, w0.z, w0.w, w1.x, w1.y, w1.z, w1.w};
#pragma unroll
            for (int r = 0; r < CAPA; ++r) {
                if (r < c) {
                    unsigned rec = w[r];
                    int sub = (int)(rec >> 16);
                    int rank = atomicAdd(&nc[sub], 1);
                    if (rank < DCAP) {
                        nl[sub * DCAP + rank] = rec & 0xFFFFu;
                    } else {
                        int sp = atomicAdd(spillCount, 1);
                        if (sp < nEdges) spill[sp] = make_uint2(rec & 0xFFFFu, (unsigned)(nodeBase + sub));
                    }
                }
            }
        }
    }
    __syncthreads();

    // gather phase: wave wv handles nodes nodeBase + wv*4 .. +3
    int lane = tid & 63;
    int wv   = tid >> 6;     // 0..15
    int half = lane >> 5;
    int cp   = lane & 31;
    float2 bv = *(const float2*)(bias + cp * 2);

#pragma unroll
    for (int i = 0; i < 4; ++i) {
        int sub = wv * 4 + i;
        int node = nodeBase + sub;
        if (node >= nNodes) continue;     // wave-uniform: no shfl divergence

        int d = nc[sub];
        if (d > DCAP) d = DCAP;
        int jend = (d + 1) & ~1;          // even bound -> both halves converge

        int myslot = (lane < d) ? (int)nl[sub * DCAP + lane] : 0;

        float2 acc = {0.f, 0.f};
        int j = half;
        for (; j + 6 < jend; j += 8) {
            int s0 = __shfl(myslot, j, 64);
            int s1 = __shfl(myslot, j + 2, 64);
            int s2 = __shfl(myslot, j + 4, 64);
            int s3 = __shfl(myslot, j + 6, 64);
            unsigned v0 = h16[(size_t)s0 * 32 + cp];
            unsigned v1 = h16[(size_t)s1 * 32 + cp];
            unsigned v2 = h16[(size_t)s2 * 32 + cp];
            unsigned v3 = h16[(size_t)s3 * 32 + cp];
            if (j + 6 >= d) v3 = 0;
            acc.x += __uint_as_float(v0 << 16);
            acc.y += __uint_as_float(v0 & 0xFFFF0000u);
            acc.x += __uint_as_float(v1 << 16);
            acc.y += __uint_as_float(v1 & 0xFFFF0000u);
            acc.x += __uint_as_float(v2 << 16);
            acc.y += __uint_as_float(v2 & 0xFFFF0000u);
            acc.x += __uint_as_float(v3 << 16);
            acc.y += __uint_as_float(v3 & 0xFFFF0000u);
        }
        for (; j < jend; j += 2) {
            int s = __shfl(myslot, j, 64);
            unsigned v = h16[(size_t)s * 32 + cp];
            if (j >= d) v = 0;
            acc.x += __uint_as_float(v << 16);
            acc.y += __uint_as_float(v & 0xFFFF0000u);
        }

        acc.x += __shfl_down(acc.x, 32, 64);
        acc.y += __shfl_down(acc.y, 32, 64);
        if (half == 0) {
            float2 o;
            o.x = acc.x + bv.x;
            o.y = acc.y + bv.y;
            *(float2*)(out + (size_t)node * OUT_CH + cp * 2) = o;
        }
    }
}

// ---------------- spill fixup (~80 edges/run) ----------------
__global__ __launch_bounds__(256) void k_spill(const uint2* __restrict__ spill,
                                               const int* __restrict__ spillCount,
                                               const unsigned* __restrict__ h16,
                                               float* __restrict__ out, int nEdges) {
    int n = *spillCount;
    if (n > nEdges) n = nEdges;
    long long total = (long long)n * 32;
    for (long long t = blockIdx.x * 256 + threadIdx.x; t < total; t += (long long)gridDim.x * 256) {
        int e = (int)(t >> 5);
        int cp = (int)(t & 31);
        uint2 sd = spill[e];
        unsigned v = h16[(size_t)sd.x * 32 + cp];
        float* o = out + (size_t)sd.y * OUT_CH + cp * 2;
        unsafeAtomicAdd(o + 0, __uint_as_float(v << 16));
        unsafeAtomicAdd(o + 1, __uint_as_float(v & 0xFFFF0000u));
    }
}

extern "C" void kernel_launch(void* const* d_in, const int* in_sizes, int n_in,
                              void* d_out, int out_size, void* d_ws, size_t ws_size,
                              hipStream_t stream) {
    const float* x    = (const float*)d_in[0];
    const int*   ei   = (const int*)d_in[1];
    const float* W    = (const float*)d_in[2];
    const float* bias = (const float*)d_in[3];
    float* out = (float*)d_out;

    int nNodes = in_sizes[0] / IN_CH;   // 50000
    int nEdges = in_sizes[1] / 2;       // 800000
    int gemmBlocks = (nNodes + TN - 1) / TN;   // 782
    int realBuckets = (nNodes + 63) / 64;      // 782

    char* p = (char*)d_ws;
    auto alloc = [&](size_t bytes) {
        char* r = p;
        p += (bytes + 255) & ~(size_t)255;
        return r;
    };
    unsigned* h16        = (unsigned*)alloc((size_t)nNodes * 32 * sizeof(unsigned));         // 6.4 MB
    unsigned* cells      = (unsigned*)alloc((size_t)PBLOCKS * NB * CAPA * sizeof(unsigned)); // 13.1 MB
    int*      cntA       = (int*)alloc((size_t)PBLOCKS * NB * sizeof(int));                  // 1.6 MB
    uint2*    spill      = (uint2*)alloc((size_t)nEdges * sizeof(uint2));                    // 6.4 MB
    int*      spillCount = (int*)alloc(sizeof(int));

    hipMemsetAsync(spillCount, 0, sizeof(int), stream);
    k_fusedA<<<gemmBlocks + PBLOCKS, 256, 0, stream>>>(x, W, h16, ei, cells, cntA,
                                                       spill, spillCount, nNodes, nEdges, gemmBlocks);
    k_fusedB<<<realBuckets, 1024, 0, stream>>>(cells, cntA, h16, bias, out,
                                               spill, spillCount, nNodes, nEdges);
    k_spill<<<64, 256, 0, stream>>>(spill, spillCount, h16, out, nEdges);
}

// Round 14
// 137.069 us; speedup vs baseline: 3.3897x; 1.0088x over previous
//
#include <hip/hip_runtime.h>

#define IN_CH 128
#define OUT_CH 64
#define TN 64            // nodes per gemm block
#define XS_STRIDE 132
#define WS_STRIDE 129

#define PBLOCKS 512      // partition role blocks
#define NB 800           // partA bucket count (bucket = dst>>6); fast path for nNodes<=51200
#define CAPA 8           // recs per (block,bucket) cell: 32 B; count lives in bits 28-31 of word0
#define DCAP 32          // per-node slot capacity; Poisson(16): P(>32)~1e-5

// fp32 -> bf16 (RNE)
__device__ __forceinline__ unsigned f2bf(float f) {
    unsigned u = __float_as_uint(f);
    return (u + 0x7FFFu + ((u >> 16) & 1u)) >> 16;
}

__device__ __forceinline__ void fma4(float4& acc, float s, const float4& wv) {
    acc.x += s * wv.x;
    acc.y += s * wv.y;
    acc.z += s * wv.z;
    acc.w += s * wv.w;
}

// ---------------- fused: gemm role | partA role, INTERLEAVED by blockIdx ----------------
// isPartA(i) = floor((i+1)*P/N) > floor(i*P/N); pid = floor(i*P/N); gid = i - pid.
// Uniform mixing => both roles resident from t=0 (VALU-bound gemm co-schedules with
// latency-bound partA on each CU; m114 overlap ~= max not sum).
__global__ __launch_bounds__(256) void k_fusedA(const float* __restrict__ x,
                                                const float* __restrict__ W,
                                                unsigned* __restrict__ h16,   // [node][32] bf16x2
                                                const int* __restrict__ ei,
                                                unsigned* __restrict__ cells,
                                                uint2* __restrict__ spill,
                                                int* __restrict__ spillCount,
                                                int nNodes, int nEdges, int totalBlocks) {
    __shared__ float smem[TN * XS_STRIDE + IN_CH * OUT_CH];  // 66.6 KB (partA uses a prefix)
    __shared__ int is64s;
    int tid = threadIdx.x;

    int i = blockIdx.x;
    long long t = (long long)i * PBLOCKS;
    int pid = (int)(t / totalBlocks);
    int isPartA = (int)((t + PBLOCKS) / totalBlocks) > pid;

    if (isPartA) {
        // ================= partA: LDS-bin edge chunk by bucket, dump coalesced =================
        unsigned* lists = (unsigned*)smem;            // NB*CAPA u32 (25.6 KB)
        int* curs = (int*)smem + NB * CAPA;           // NB ints (3.2 KB)
        for (int k = tid; k < NB; k += 256) curs[k] = 0;
        if (tid == 0) {
            int v = 1;
#pragma unroll
            for (int j = 0; j < 16; ++j)
                if (ei[2 * j + 1] != 0) v = 0;
            is64s = v;
        }
        __syncthreads();
        int is64 = is64s;

        int chunk = (nEdges + PBLOCKS - 1) / PBLOCKS;
        int e0 = pid * chunk;
        int e1 = min(e0 + chunk, nEdges);
        for (int e = e0 + tid; e < e1; e += 256) {
            int src, dst;
            if (is64) {
                src = ((const int2*)ei)[e].x;
                dst = ((const int2*)ei)[nEdges + e].x;
            } else {
                src = ei[e];
                dst = ei[nEdges + e];
            }
            if ((unsigned)src >= (unsigned)nNodes) src = 0;
            if ((unsigned)dst >= (unsigned)nNodes) dst = 0;
            int bucket = dst >> 6;
            int rank = (bucket < NB) ? atomicAdd(&curs[bucket], 1) : CAPA;
            if (rank < CAPA) {
                lists[bucket * CAPA + rank] = (unsigned)src | ((unsigned)(dst & 63) << 16);
            } else {
                int sp = atomicAdd(spillCount, 1);   // ~80 edges/run
                if (sp < nEdges) spill[sp] = make_uint2((unsigned)src, (unsigned)dst);
            }
        }
        __syncthreads();

        // dump; embed count in bits 28-31 of each cell's word0 (recs are 22-bit)
        size_t base = (size_t)pid * NB;
        uint4* cells4 = (uint4*)(cells + base * CAPA);
        for (int j = tid; j < NB * CAPA / 4; j += 256) {
            uint4 v = *(const uint4*)(lists + 4 * j);
            if ((j & 1) == 0) {
                int cell = j >> 1;
                v.x = (v.x & 0x0FFFFFFFu) | ((unsigned)min(curs[cell], CAPA) << 28);
            }
            cells4[j] = v;
        }
        return;
    }

    // ================= gemm: h = x @ W^T, bf16 output =================
    int gid = i - pid;
    float* u  = smem;
    float* wt = smem + TN * XS_STRIDE;
    int nodeBase = gid * TN;

    {
        const float4* W4 = (const float4*)W;
        for (int j = tid; j < IN_CH * OUT_CH / 4; j += 256) {
            float4 v = W4[j];
            int o = j >> 5;
            int k = (j & 31) * 4;
            float* d = u + o * WS_STRIDE + k;
            d[0] = v.x; d[1] = v.y; d[2] = v.z; d[3] = v.w;
        }
    }
    __syncthreads();
    {
        int o = tid & 63;
        int k0 = (tid >> 6) * 32;
#pragma unroll 8
        for (int k = k0; k < k0 + 32; ++k)
            wt[k * OUT_CH + o] = u[o * WS_STRIDE + k];
    }
    __syncthreads();
    {
        int remRows = nNodes - nodeBase;
        if (remRows > TN) remRows = TN;
        const float4* X4 = (const float4*)(x + (size_t)nodeBase * IN_CH);
        for (int j = tid; j < TN * IN_CH / 4; j += 256) {
            int r = j >> 5;
            int k = (j & 31) * 4;
            float4 v = make_float4(0.f, 0.f, 0.f, 0.f);
            if (r < remRows) v = X4[j];
            *(float4*)(u + r * XS_STRIDE + k) = v;
        }
    }
    __syncthreads();

    int tx = tid & 15;
    int ty = tid >> 4;

    float4 acc[4];
#pragma unroll
    for (int q = 0; q < 4; ++q) acc[q] = make_float4(0.f, 0.f, 0.f, 0.f);

    const float* wcol = wt + tx * 4;
#pragma unroll 4
    for (int k = 0; k < IN_CH; k += 4) {
        float4 w0 = *(const float4*)(wcol + (k + 0) * OUT_CH);
        float4 w1 = *(const float4*)(wcol + (k + 1) * OUT_CH);
        float4 w2 = *(const float4*)(wcol + (k + 2) * OUT_CH);
        float4 w3 = *(const float4*)(wcol + (k + 3) * OUT_CH);
#pragma unroll
        for (int q = 0; q < 4; ++q) {
            float4 a = *(const float4*)(u + (ty * 4 + q) * XS_STRIDE + k);
            fma4(acc[q], a.x, w0);
            fma4(acc[q], a.y, w1);
            fma4(acc[q], a.z, w2);
            fma4(acc[q], a.w, w3);
        }
    }

#pragma unroll
    for (int q = 0; q < 4; ++q) {
        int n = nodeBase + ty * 4 + q;
        if (n < nNodes) {
            uint2 pk;
            pk.x = f2bf(acc[q].x) | (f2bf(acc[q].y) << 16);
            pk.y = f2bf(acc[q].z) | (f2bf(acc[q].w) << 16);
            *(uint2*)(h16 + (size_t)n * 32 + tx * 2) = pk;
        }
    }
}

// ---------------- fused: partB (bin bucket cells to LDS) + gather (from LDS) ----------------
__global__ __launch_bounds__(1024) void k_fusedB(const unsigned* __restrict__ cells,
                                                 const unsigned* __restrict__ h16,
                                                 const float* __restrict__ bias,
                                                 float* __restrict__ out,
                                                 uint2* __restrict__ spill,
                                                 int* __restrict__ spillCount,
                                                 int nNodes, int nEdges) {
    __shared__ unsigned nl[64 * DCAP];   // 8 KB
    __shared__ int nc[64];
    int tid = threadIdx.x;
    int b = blockIdx.x;
    int nodeBase = b * 64;

    if (tid < 64) nc[tid] = 0;
    __syncthreads();

    if (b < NB) {
        for (int blk = tid; blk < PBLOCKS; blk += 1024) {
            const unsigned* cb = cells + ((size_t)blk * NB + b) * CAPA;  // 32-B aligned
            uint4 w0 = *(const uint4*)(cb + 0);
            uint4 w1 = *(const uint4*)(cb + 4);
            int c = (int)(w0.x >> 28);            // count embedded in word0
            if (c > CAPA) c = CAPA;
            unsigned w[CAPA] = {w0.x, w0.y, w0.z, w0.w, w1.x, w1.y, w1.z, w1.w};
#pragma unroll
            for (int r = 0; r < CAPA; ++r) {
                if (r < c) {
                    unsigned rec = w[r];
                    int sub = (int)(rec >> 16) & 63;   // mask strips count bits from word0
                    int rank = atomicAdd(&nc[sub], 1);
                    if (rank < DCAP) {
                        nl[sub * DCAP + rank] = rec & 0xFFFFu;
                    } else {
                        int sp = atomicAdd(spillCount, 1);   // ~1 node/run exceeds 32
                        if (sp < nEdges) spill[sp] = make_uint2(rec & 0xFFFFu, (unsigned)(nodeBase + sub));
                    }
                }
            }
        }
    }
    __syncthreads();

    // gather phase: wave wv handles nodes nodeBase + wv*4 .. +3
    int lane = tid & 63;
    int wv   = tid >> 6;     // 0..15
    int half = lane >> 5;
    int cp   = lane & 31;
    float2 bv = *(const float2*)(bias + cp * 2);

#pragma unroll
    for (int q = 0; q < 4; ++q) {
        int sub = wv * 4 + q;
        int node = nodeBase + sub;
        if (node >= nNodes) continue;     // wave-uniform: no shfl divergence

        int d = nc[sub];
        if (d > DCAP) d = DCAP;
        int jend = (d + 1) & ~1;          // even bound -> both halves converge

        int myslot = (lane < d) ? (int)nl[sub * DCAP + lane] : 0;

        float2 acc = {0.f, 0.f};
        int j = half;
        for (; j + 6 < jend; j += 8) {
            int s0 = __shfl(myslot, j, 64);
            int s1 = __shfl(myslot, j + 2, 64);
            int s2 = __shfl(myslot, j + 4, 64);
            int s3 = __shfl(myslot, j + 6, 64);
            unsigned v0 = h16[(size_t)s0 * 32 + cp];
            unsigned v1 = h16[(size_t)s1 * 32 + cp];
            unsigned v2 = h16[(size_t)s2 * 32 + cp];
            unsigned v3 = h16[(size_t)s3 * 32 + cp];
            if (j + 6 >= d) v3 = 0;
            acc.x += __uint_as_float(v0 << 16);
            acc.y += __uint_as_float(v0 & 0xFFFF0000u);
            acc.x += __uint_as_float(v1 << 16);
            acc.y += __uint_as_float(v1 & 0xFFFF0000u);
            acc.x += __uint_as_float(v2 << 16);
            acc.y += __uint_as_float(v2 & 0xFFFF0000u);
            acc.x += __uint_as_float(v3 << 16);
            acc.y += __uint_as_float(v3 & 0xFFFF0000u);
        }
        for (; j < jend; j += 2) {
            int s = __shfl(myslot, j, 64);
            unsigned v = h16[(size_t)s * 32 + cp];
            if (j >= d) v = 0;
            acc.x += __uint_as_float(v << 16);
            acc.y += __uint_as_float(v & 0xFFFF0000u);
        }

        acc.x += __shfl_down(acc.x, 32, 64);
        acc.y += __shfl_down(acc.y, 32, 64);
        if (half == 0) {
            float2 o;
            o.x = acc.x + bv.x;
            o.y = acc.y + bv.y;
            *(float2*)(out + (size_t)node * OUT_CH + cp * 2) = o;
        }
    }
}

// ---------------- spill fixup (~80 edges/run) ----------------
__global__ __launch_bounds__(256) void k_spill(const uint2* __restrict__ spill,
                                               const int* __restrict__ spillCount,
                                               const unsigned* __restrict__ h16,
                                               float* __restrict__ out, int nEdges) {
    int n = *spillCount;
    if (n > nEdges) n = nEdges;
    long long total = (long long)n * 32;
    for (long long t = blockIdx.x * 256 + threadIdx.x; t < total; t += (long long)gridDim.x * 256) {
        int e = (int)(t >> 5);
        int cp = (int)(t & 31);
        uint2 sd = spill[e];
        unsigned v = h16[(size_t)sd.x * 32 + cp];
        float* o = out + (size_t)sd.y * OUT_CH + cp * 2;
        unsafeAtomicAdd(o + 0, __uint_as_float(v << 16));
        unsafeAtomicAdd(o + 1, __uint_as_float(v & 0xFFFF0000u));
    }
}

extern "C" void kernel_launch(void* const* d_in, const int* in_sizes, int n_in,
                              void* d_out, int out_size, void* d_ws, size_t ws_size,
                              hipStream_t stream) {
    const float* x    = (const float*)d_in[0];
    const int*   ei   = (const int*)d_in[1];
    const float* W    = (const float*)d_in[2];
    const float* bias = (const float*)d_in[3];
    float* out = (float*)d_out;

    int nNodes = in_sizes[0] / IN_CH;   // 50000
    int nEdges = in_sizes[1] / 2;       // 800000
    int gemmBlocks = (nNodes + TN - 1) / TN;   // 782
    int realBuckets = (nNodes + 63) / 64;      // 782
    int totalBlocks = gemmBlocks + PBLOCKS;    // 1294

    char* p = (char*)d_ws;
    auto alloc = [&](size_t bytes) {
        char* r = p;
        p += (bytes + 255) & ~(size_t)255;
        return r;
    };
    unsigned* h16        = (unsigned*)alloc((size_t)nNodes * 32 * sizeof(unsigned));         // 6.4 MB
    unsigned* cells      = (unsigned*)alloc((size_t)PBLOCKS * NB * CAPA * sizeof(unsigned)); // 13.1 MB
    uint2*    spill      = (uint2*)alloc((size_t)nEdges * sizeof(uint2));                    // 6.4 MB
    int*      spillCount = (int*)alloc(sizeof(int));

    hipMemsetAsync(spillCount, 0, sizeof(int), stream);
    k_fusedA<<<totalBlocks, 256, 0, stream>>>(x, W, h16, ei, cells,
                                              spill, spillCount, nNodes, nEdges, totalBlocks);
    k_fusedB<<<realBuckets, 1024, 0, stream>>>(cells, h16, bias, out,
                                               spill, spillCount, nNodes, nEdges);
    k_spill<<<64, 256, 0, stream>>>(spill, spillCount, h16, out, nEdges);
}